// Round 1
// baseline (454.814 us; speedup 1.0000x reference)
//
#include <hip/hip_runtime.h>
#include <hip/hip_bf16.h>

// Network: bidirectional LSTM (T=256, B=1024, E=300, H=50) + small MLP head.
// Key insight: h_bw[0] needs only ONE backward step (zero initial state), and
// the input projection x@Wx is hoisted into a per-VOCAB precompute P = E@Wx.

#define VOCAB 50000
#define EMB   300
#define HID   50
#define GATES 200          // 4*H
#define BATCH 1024
#define TT    256          // 2*MAX_LEN
#define BN_SCALE 0.9995003746877732f   // 1/sqrt(1.001)

__device__ __forceinline__ float sigm(float x) {
    return 1.0f / (1.0f + __expf(-x));
}
__device__ __forceinline__ float tanh_f(float x) {
    // tanh(x) = 1 - 2/(e^{2x}+1); saturates correctly for |x| large (inf -> 1/-1)
    return 1.0f - 2.0f / (__expf(2.0f * x) + 1.0f);
}

// ---------------------------------------------------------------------------
// K1: P[v][j] = sum_e E[v][e] * Wx[e][j]   (Wx = W_fw rows 0..299)
// 32 vocab rows per block; E tile staged in LDS; thread j<200 owns one column
// with 32-row register accumulation (w-values reused 32x from registers).
// ---------------------------------------------------------------------------
__global__ __launch_bounds__(256) void vocab_proj(const float* __restrict__ E,
                                                  const float* __restrict__ Wx,
                                                  float* __restrict__ P) {
    __shared__ __align__(16) float sE[32 * EMB];   // 38400 B
    const int v0 = blockIdx.x * 32;
    const int t  = threadIdx.x;

    const int base = v0 * EMB;
    const int vmax = VOCAB * EMB;
    for (int idx = t; idx < 32 * EMB; idx += 256) {
        int g = base + idx;
        sE[idx] = (g < vmax) ? E[g] : 0.0f;
    }
    __syncthreads();
    if (t >= GATES) return;

    float acc[32];
#pragma unroll
    for (int r = 0; r < 32; ++r) acc[r] = 0.0f;

    for (int e = 0; e < EMB; e += 4) {
        const float w0 = Wx[(e + 0) * GATES + t];
        const float w1 = Wx[(e + 1) * GATES + t];
        const float w2 = Wx[(e + 2) * GATES + t];
        const float w3 = Wx[(e + 3) * GATES + t];
#pragma unroll
        for (int r = 0; r < 32; ++r) {
            const float4 ev = *reinterpret_cast<const float4*>(&sE[r * EMB + e]);
            acc[r] = fmaf(ev.w, w3, fmaf(ev.z, w2, fmaf(ev.y, w1, fmaf(ev.x, w0, acc[r]))));
        }
    }
#pragma unroll
    for (int r = 0; r < 32; ++r) {
        const int v = v0 + r;
        if (v < VOCAB) P[v * GATES + t] = acc[r];
    }
}

// ---------------------------------------------------------------------------
// K2: forward LSTM, one block per batch row, 256 steps.
// Thread j<200 owns gate column j (Whh[:,j] cached in 50 VGPRs).
// Per step: g_j = P[tok] + b + h·Whh[:,j]  -> LDS exchange -> lanes<50 update
// (c in register), h back to LDS. Next step's P row prefetched early.
// ---------------------------------------------------------------------------
__global__ __launch_bounds__(256) void lstm_fw(const int* __restrict__ x1,
                                               const int* __restrict__ x2,
                                               const float* __restrict__ P,
                                               const float* __restrict__ Wfw,
                                               const float* __restrict__ bfw,
                                               float* __restrict__ feat) {
    const int b = blockIdx.x;
    const int j = threadIdx.x;

    __shared__ float sh[HID];     // hidden state
    __shared__ float sg[GATES];   // gate pre-activations

    float whh[HID];
    float bj = 0.0f;
    if (j < GATES) {
        bj = bfw[j];
#pragma unroll
        for (int k = 0; k < HID; ++k)
            whh[k] = Wfw[(EMB + k) * GATES + j];   // rows 300..349
    }
    float c = 0.0f;
    if (j < HID) sh[j] = 0.0f;
    __syncthreads();

    int tok0 = x1[b * 128];
    float pf = (j < GATES) ? P[tok0 * GATES + j] : 0.0f;

    for (int t = 0; t < TT; ++t) {
        // prefetch next step's projected input (tokens are data-independent)
        float pfn = 0.0f;
        if (t < TT - 1) {
            const int tn   = t + 1;
            const int tokn = (tn < 128) ? x1[b * 128 + tn] : x2[b * 128 + tn - 128];
            if (j < GATES) pfn = P[tokn * GATES + j];
        }

        if (j < GATES) {
            float g0 = pf + bj, g1 = 0.0f;
#pragma unroll
            for (int k = 0; k < HID; k += 2) {
                g0 = fmaf(whh[k],     sh[k],     g0);
                g1 = fmaf(whh[k + 1], sh[k + 1], g1);
            }
            sg[j] = g0 + g1;
        }
        __syncthreads();

        if (j < HID) {
            const float gi = sg[j];
            const float gj = sg[j + HID];
            const float gf = sg[j + 2 * HID];
            const float go = sg[j + 3 * HID];
            c = c * sigm(gf + 1.0f) + sigm(gi) * tanh_f(gj);
            sh[j] = tanh_f(c) * sigm(go);
        }
        __syncthreads();
        pf = pfn;
    }

    if (j < HID) feat[b * (2 * HID) + j] = sh[j];
}

// ---------------------------------------------------------------------------
// K3: backward LSTM needs only ONE step (h_bw[0], zero init state, h part of
// W unused since h=0), fused with BN-scale + MLP head (100 -> 25 -> 3).
// One block per batch row.
// ---------------------------------------------------------------------------
__global__ __launch_bounds__(256) void bw_mlp(const int* __restrict__ x2,
                                              const float* __restrict__ E,
                                              const float* __restrict__ Wbw,
                                              const float* __restrict__ bbw,
                                              const float* __restrict__ W1,
                                              const float* __restrict__ b1,
                                              const float* __restrict__ W2,
                                              const float* __restrict__ b2,
                                              const float* __restrict__ featfw,
                                              float* __restrict__ out) {
    const int b = blockIdx.x;
    const int t = threadIdx.x;

    __shared__ __align__(16) float sx[EMB + 4];
    __shared__ float sf[2 * HID];
    __shared__ float sg[GATES];
    __shared__ float sh1[25];

    const int tok = x2[b * 128 + 127];   // xs[T-1] token
    for (int e = t; e < EMB; e += 256) sx[e] = E[tok * EMB + e];
    if (t < HID) sf[t] = featfw[b * (2 * HID) + t];
    __syncthreads();

    if (t < GATES) {
        float g0 = bbw[t], g1 = 0.0f, g2 = 0.0f, g3 = 0.0f;
        for (int e = 0; e < EMB; e += 4) {
            g0 = fmaf(sx[e + 0], Wbw[(e + 0) * GATES + t], g0);
            g1 = fmaf(sx[e + 1], Wbw[(e + 1) * GATES + t], g1);
            g2 = fmaf(sx[e + 2], Wbw[(e + 2) * GATES + t], g2);
            g3 = fmaf(sx[e + 3], Wbw[(e + 3) * GATES + t], g3);
        }
        sg[t] = (g0 + g1) + (g2 + g3);
    }
    __syncthreads();

    if (t < HID) {
        // c=0: c2 = sigm(i)*tanh(j); h = tanh(c2)*sigm(o)
        const float c2 = sigm(sg[t]) * tanh_f(sg[t + HID]);
        sf[HID + t] = tanh_f(c2) * sigm(sg[t + 3 * HID]);
    }
    __syncthreads();

    if (t < 25) {
        float a = 0.0f;
#pragma unroll 4
        for (int k = 0; k < 2 * HID; ++k)
            a = fmaf(sf[k], W1[k * 25 + t], a);
        a = fmaf(a, BN_SCALE, b1[t]);
        sh1[t] = fmaxf(a, 0.0f);
    }
    __syncthreads();

    if (t < 3) {
        float a = b2[t];
#pragma unroll
        for (int k = 0; k < 25; ++k)
            a = fmaf(sh1[k], W2[k * 3 + t], a);
        out[b * 3 + t] = a * BN_SCALE;
    }
}

// ---------------------------------------------------------------------------
extern "C" void kernel_launch(void* const* d_in, const int* in_sizes, int n_in,
                              void* d_out, int out_size, void* d_ws, size_t ws_size,
                              hipStream_t stream) {
    const int*   x1  = (const int*)d_in[0];
    const int*   x2  = (const int*)d_in[1];
    const float* E   = (const float*)d_in[2];
    const float* Wfw = (const float*)d_in[3];
    const float* bfw = (const float*)d_in[4];
    const float* Wbw = (const float*)d_in[5];
    const float* bbw = (const float*)d_in[6];
    const float* W1  = (const float*)d_in[7];
    const float* b1  = (const float*)d_in[8];
    const float* W2  = (const float*)d_in[9];
    const float* b2  = (const float*)d_in[10];
    float* out = (float*)d_out;

    // ws layout: P [50000*200] f32 (40 MB) | feat [1024*100] f32
    float* P    = (float*)d_ws;
    float* feat = P + (size_t)VOCAB * GATES;

    vocab_proj<<<(VOCAB + 31) / 32, 256, 0, stream>>>(E, Wfw, P);
    lstm_fw<<<BATCH, 256, 0, stream>>>(x1, x2, P, Wfw, bfw, feat);
    bw_mlp<<<BATCH, 256, 0, stream>>>(x2, E, Wbw, bbw, W1, b1, W2, b2, feat, out);
}